// Round 17
// baseline (661.965 us; speedup 1.0000x reference)
//
#include <hip/hip_runtime.h>
#include <math.h>

#define KNB 20
constexpr float BN_INV = 0.9999950000374997f;  // 1/sqrt(1+1e-5)
constexpr float SLOPE = 0.2f;

__device__ __forceinline__ float lrelu(float v){ return v >= 0.f ? v : SLOPE*v; }

#define DPPMAX(ctrl) { unsigned lo=(unsigned)bk, hi=(unsigned)(bk>>32); \
  unsigned lo2=(unsigned)__builtin_amdgcn_mov_dpp((int)lo, ctrl, 0xF, 0xF, true); \
  unsigned hi2=(unsigned)__builtin_amdgcn_mov_dpp((int)hi, ctrl, 0xF, 0xF, true); \
  unsigned long long ok=((unsigned long long)hi2<<32)|lo2; if(ok>bk)bk=ok; }

// all-lanes 64-wide max of u64 keys: 4 DPP (cyclic, row-converging) + 2 shfl_xor
__device__ __forceinline__ unsigned long long wave_max64_all(unsigned long long bk){
  DPPMAX(0xB1) DPPMAX(0x4E) DPPMAX(0x124) DPPMAX(0x128)
  { unsigned long long ok = __shfl_xor(bk, 16); if (ok > bk) bk = ok; }
  { unsigned long long ok = __shfl_xor(bk, 32); if (ok > bk) bk = ok; }
  return bk;
}

// ---------------- prep: transpose x + combine conv2/conv3 weights ----------------
__global__ __launch_bounds__(256) void prep_kernel(const float* __restrict__ x, float* __restrict__ pts,
                            const float* __restrict__ conv2w, float* __restrict__ Wc2,
                            const float* __restrict__ conv3w, float* __restrict__ Wc3){
  int i = blockIdx.x*256 + threadIdx.x;
  if (i < 16*1024){
    int b = i >> 10, n = i & 1023;
    const float* xb = x + (size_t)b*3*1024;
    float* p = pts + (size_t)i*3;
    p[0]=xb[n]; p[1]=xb[1024+n]; p[2]=xb[2048+n];
  } else if (i < 16*1024 + 64*64){
    int e = i - 16*1024;
    int o = e >> 6, c = e & 63;
    float wa=conv2w[(size_t)o*256+c], wb=conv2w[(size_t)o*256+64+c];
    float wc=conv2w[(size_t)o*256+128+c], wd=conv2w[(size_t)o*256+192+c];
    Wc2[((size_t)0*64+o)*64+c]=wa+wb; Wc2[((size_t)1*64+o)*64+c]=wc+wd; Wc2[((size_t)2*64+o)*64+c]=wa+wc;
  } else if (i < 16*1024 + 64*64 + 128*64){
    int e = i - 16*1024 - 64*64;
    int o = e >> 6, c = e & 63;
    float wa=conv3w[(size_t)o*256+c], wb=conv3w[(size_t)o*256+64+c];
    float wc=conv3w[(size_t)o*256+128+c], wd=conv3w[(size_t)o*256+192+c];
    Wc3[((size_t)0*128+o)*64+c]=wa+wb; Wc3[((size_t)1*128+o)*64+c]=wc+wd; Wc3[((size_t)2*128+o)*64+c]=wa+wc;
  }
}

// ---------------- kNN row top-20: u64 keys (order-embedded float) + DPP reduce ----------------
template<int N>
__device__ int knn_row(const float4* sp, int row, int lane){
#pragma clang fp contract(off)
  constexpr int E = N/64;
  float4 P = sp[row];
  unsigned long long key[E];
  #pragma unroll
  for (int i=0;i<E;++i){
    float4 Q = sp[lane + i*64];
    float inner = (P.x*Q.x + P.y*Q.y) + P.z*Q.z;
    float nd = (2.0f*inner - P.w) - Q.w;
    unsigned u = __float_as_uint(nd);
    u ^= ((unsigned)((int)u >> 31)) | 0x80000000u;   // monotone embed (all floats)
    key[i] = ((unsigned long long)u << 32) | (unsigned)(~(lane + i*64));
  }
  int myout = 0;
  for (int j=0;j<KNB;++j){
    unsigned long long best = key[0];
    #pragma unroll
    for (int i=1;i<E;++i) best = key[i] > best ? key[i] : best;
    best = wave_max64_all(best);
    int wid = (int)(~(unsigned)best);
    if (lane == j) myout = wid;
    if (lane == (wid & 63)){
      int slot = wid >> 6;
      #pragma unroll
      for (int i=0;i<E;++i) if (i == slot) key[i] = 0ULL;
    }
  }
  return myout;
}

// ---------------- kNN core: one wave per query row; output to global or per-wave LDS ----------------
template<int N, bool TOGLOBAL>
__device__ void knn_core(const float* __restrict__ pts, int* __restrict__ idx_global,
                         int* __restrict__ sOut, int chunk, int b, float4* sp){
  int t = threadIdx.x;
  const float* pb = pts + (size_t)b*N*3;
  for (int e = t; e < N; e += 256){
    float x0=pb[e*3], x1=pb[e*3+1], x2=pb[e*3+2];
    sp[e] = make_float4(x0, x1, x2, (x0*x0 + x1*x1) + x2*x2);
  }
  __syncthreads();
  int wave = t >> 6, lane = t & 63;
  int row = chunk*4 + wave;
  int myout = knn_row<N>(sp, row, lane);
  if (TOGLOBAL){
    if (lane < KNB) idx_global[((size_t)b*N + row)*KNB + lane] = myout;
  } else {
    if (lane < KNB) sOut[lane] = myout;
  }
}

// ---------------- cov + analytic eig for one row (single thread), points from LDS ----------------
__device__ void cov_eig_row(const float4* sp, const int* sIdxRow, int row, float* ev){
  float cx = sp[row].x, cy = sp[row].y, cz = sp[row].z;
  float c00=0,c01=0,c02=0,c11=0,c12=0,c22=0;
  for (int k=0;k<KNB;++k){
    int m = sIdxRow[k];
    float dx = sp[m].x-cx, dy = sp[m].y-cy, dz = sp[m].z-cz;
    c00 += dx*dx; c01 += dx*dy; c02 += dx*dz;
    c11 += dy*dy; c12 += dy*dz; c22 += dz*dz;
  }
  double a00=c00,a01=c01,a02=c02,a11=c11,a12=c12,a22=c22;
  double p1 = a01*a01 + a02*a02 + a12*a12;
  double q = (a00+a11+a22)/3.0;
  double b00=a00-q, b11=a11-q, b22=a22-q;
  double p2 = b00*b00+b11*b11+b22*b22 + 2.0*p1;
  double e0,e1,e2;
  if (p2 <= 0.0){
    e0=e1=e2=q;
  } else {
    double p = sqrt(p2/6.0);
    double det = b00*(b11*b22 - a12*a12) - a01*(a01*b22 - a12*a02) + a02*(a01*a12 - b11*a02);
    double r = det / (2.0*p*p*p);
    r = fmin(1.0, fmax(-1.0, r));
    double phi = acos(r)/3.0;
    double big = q + 2.0*p*cos(phi);
    double sml = q + 2.0*p*cos(phi + 2.0943951023931953);
    double mid = 3.0*q - big - sml;
    e0 = sml; e1 = mid; e2 = big;
  }
  ev[0]=(float)e0; ev[1]=(float)e1; ev[2]=(float)e2;
}

// ---------------- fused kNN + cov_eig body: RPW rows per wave ----------------
template<int N, int RPW>
__device__ void knn_cov_body(const float* __restrict__ pts, int* __restrict__ idx,
                             float* __restrict__ eigval, int cb, int b,
                             float4* sp, int (*sIdx)[KNB]){
  constexpr int ROWS = 4*RPW;
  int t = threadIdx.x;
  const float* pb = pts + (size_t)b*N*3;
  for (int e = t; e < N; e += 256){
    float x0=pb[e*3], x1=pb[e*3+1], x2=pb[e*3+2];
    sp[e] = make_float4(x0, x1, x2, (x0*x0 + x1*x1) + x2*x2);
  }
  __syncthreads();
  int wave = t >> 6, lane = t & 63;
  #pragma unroll
  for (int r=0; r<RPW; ++r){
    int lr = wave*RPW + r;
    int row = cb*ROWS + lr;
    int myout = knn_row<N>(sp, row, lane);
    if (lane < KNB){
      sIdx[lr][lane] = myout;
      idx[((size_t)b*N + row)*KNB + lane] = myout;
    }
  }
  __syncthreads();
  if (t < ROWS){
    int row = cb*ROWS + t;
    cov_eig_row(sp, &sIdx[t][0], row, eigval + ((size_t)b*N + row)*3);
  }
}

template<int N, int RPW>
__global__ __launch_bounds__(256) void knn_cov_kernel(const float* __restrict__ pts,
    int* __restrict__ idx, float* __restrict__ eigval){
  __shared__ float4 sp[N];
  __shared__ int sIdx[4*RPW][KNB];
  knn_cov_body<N,RPW>(pts, idx, eigval, blockIdx.x, blockIdx.y, sp, sIdx);
}

// ---------------- FPS v5: 4-wave split, u64 keys, key-only all-DPP butterfly ----------------
#define DECLQ4(i) float4 Q##i = sp[(i)*256 + tid]; float D##i = 1e10f; \
  asm volatile("" : "+v"(Q##i.x), "+v"(Q##i.y), "+v"(Q##i.z));
#define UPD4(i, B) { float dx=Q##i.x-L.x; float dy=Q##i.y-L.y; float dz=Q##i.z-L.z; \
  float dd=fminf(D##i,(dx*dx+dy*dy)+dz*dz); D##i=dd; \
  unsigned long long k=((unsigned long long)__float_as_uint(dd)<<32)|(unsigned long long)(nl-(unsigned)((i)*256)); \
  if(k>B)B=k; }
#define FPS_STEP_TAIL \
      DPPMAX(0xB1) DPPMAX(0x4E) DPPMAX(0x124) DPPMAX(0x128) DPPMAX(0x142) DPPMAX(0x143) \
      if (lane == 63) rk[((s&1)<<2) | w] = bk; \
      __syncthreads(); \
      { const unsigned long long* rp = rk + ((s&1)<<2); \
        unsigned long long k0=rp[0], k1=rp[1], k2=rp[2], k3=rp[3]; \
        unsigned long long km1 = k0>k1?k0:k1, km2 = k2>k3?k2:k3; \
        unsigned long long kk = km1>km2?km1:km2; \
        last = (int)(~(unsigned int)kk); } \
      if (tid==0) idout[(size_t)b*M + s] = last;

template<int N, int M>
__device__ void fps_body4(const float* __restrict__ pts, int* __restrict__ idout,
                          int b, float4* sp, unsigned long long* rk){
#pragma clang fp contract(off)
  constexpr int E4 = N/256;
  int tid = threadIdx.x;
  const float* pb = pts + (size_t)b*N*3;
  for (int e=tid; e<N; e+=256){
    sp[e] = make_float4(pb[e*3], pb[e*3+1], pb[e*3+2], 0.f);
  }
  __syncthreads();
  __builtin_amdgcn_s_setprio(1);
  int lane = tid & 63, w = tid >> 6;
  unsigned int nl = ~(unsigned int)tid;
  int last = 0;
  if (tid==0) idout[(size_t)b*M] = 0;
  if constexpr (E4 == 4){
    DECLQ4(0) DECLQ4(1) DECLQ4(2) DECLQ4(3)
    for (int s=1; s<M; ++s){
      float4 L = sp[last];
      unsigned long long b0=0ULL,b1=0ULL,b2=0ULL,b3=0ULL;
      UPD4(0,b0) UPD4(1,b1) UPD4(2,b2) UPD4(3,b3)
      unsigned long long kl_ = b0>b1?b0:b1, kh_ = b2>b3?b2:b3;
      unsigned long long bk = kl_>kh_?kl_:kh_;
      FPS_STEP_TAIL
    }
  } else {
    DECLQ4(0) DECLQ4(1)
    for (int s=1; s<M; ++s){
      float4 L = sp[last];
      unsigned long long b0=0ULL,b1=0ULL;
      UPD4(0,b0) UPD4(1,b1)
      unsigned long long bk = b0>b1?b0:b1;
      FPS_STEP_TAIL
    }
  }
}

// ---------------- stage1 body: kNN(eig1) + 13-ch feat + conv1 + BN + lrelu + max_k ----------------
__device__ void stage1_body(
    const float* __restrict__ eig, const float* __restrict__ pts,
    const int* __restrict__ idx_eu,
    const float* __restrict__ w, const float* __restrict__ g, const float* __restrict__ bb,
    float* __restrict__ x1, int chunk, int b,
    float4* sp, int (*sIei)[KNB], float (*feat)[13][KNB]){
  constexpr int N = 1024;
  int t = threadIdx.x, wave = t>>6, lane = t&63;
  knn_core<N,false>(eig, nullptr, &sIei[wave][0], chunk, b, sp);
  int row = chunk*4 + wave;
  size_t i = (size_t)b*N + row;
  const float* pb = pts + (size_t)b*N*3;
  if (lane < KNB){
    int ieu = idx_eu[i*KNB + lane];
    int iei = sIei[wave][lane];
    float4 ne4 = sp[iei];
    float4 ee4 = sp[row];
    float d2 = 0.f;
    #pragma unroll
    for (int f=0; f<3; ++f){
      float nx = pb[ieu*3+f], xx = pb[row*3+f];
      float dfv = nx - xx;
      feat[wave][f][lane] = dfv; feat[wave][3+f][lane] = nx;
      float ne = (f==0)? ne4.x : ((f==1)? ne4.y : ne4.z);
      float ee = (f==0)? ee4.x : ((f==1)? ee4.y : ee4.z);
      feat[wave][6+f][lane] = ne - ee; feat[wave][9+f][lane] = ne;
      d2 += dfv*dfv;
    }
    feat[wave][12][lane] = sqrtf(fmaxf(d2, 1e-12f));
  }
  __syncthreads();
  float wr[13];
  #pragma unroll
  for (int c=0;c<13;++c) wr[c] = w[lane*13+c];
  float sg = BN_INV * g[lane], sb = bb[lane];
  float mx = -INFINITY;
  for (int k=0;k<KNB;++k){
    float s = 0.f;
    #pragma unroll
    for (int c=0;c<13;++c) s = fmaf(wr[c], feat[wave][c][k], s);
    mx = fmaxf(mx, lrelu(fmaf(s, sg, sb)));
  }
  x1[i*64 + lane] = mx;
}

// ---------------- mega1: fps1 (blocks 0..15) || knn_ei+stage1 (rest) ----------------
__global__ __launch_bounds__(256, 1) void mega1_kernel(
    const float* __restrict__ pts1, int* __restrict__ fps_id,
    const float* __restrict__ eig1, const int* __restrict__ idx_eu,
    const float* __restrict__ w, const float* __restrict__ g, const float* __restrict__ bb,
    float* __restrict__ x1){
  __shared__ float4 sp[1024];
  __shared__ int sIei[4][KNB];
  __shared__ float feat[4][13][KNB];
  __shared__ unsigned long long rk[8];
  if (blockIdx.x < 16){
    fps_body4<1024,512>(pts1, fps_id, blockIdx.x, sp, rk);
  } else {
    int bx = blockIdx.x - 16;
    stage1_body(eig1, pts1, idx_eu, w, g, bb, x1, bx & 255, bx >> 8, sp, sIei, feat);
  }
}

// ---------------- fused: kNN(eig) + gathermax ----------------
template<int COUT, int N>
__device__ void gm_body(const float* __restrict__ eig,
    const float* __restrict__ PQR, int Mtot,
    const int* __restrict__ idx_eu,
    const float* __restrict__ g, const float* __restrict__ bb,
    float* __restrict__ xout, int chunk, int b, float4* sp, int* sIeiW){
  int t = threadIdx.x, wave = t>>6, lane = t&63;
  knn_core<N,false>(eig, nullptr, sIeiW, chunk, b, sp);
  __syncthreads();
  int row = chunk*4 + wave;
  size_t i = (size_t)b*N + row;
  const float* P = PQR;
  const float* Q = PQR + (size_t)Mtot*COUT;
  const float* R = PQR + (size_t)2*Mtot*COUT;
  for (int o = lane; o < COUT; o += 64){
    float base = R[i*COUT + o];
    float sg = BN_INV*g[o], sb = bb[o];
    float mx = -INFINITY;
    for (int k=0;k<KNB;++k){
      int eu = idx_eu[i*KNB + k];
      int ei = sIeiW[k];
      float v = P[((size_t)b*N + eu)*COUT + o] + Q[((size_t)b*N + ei)*COUT + o] - base;
      mx = fmaxf(mx, lrelu(fmaf(v, sg, sb)));
    }
    xout[i*COUT + o] = mx;
  }
}

template<int COUT, int N>
__global__ __launch_bounds__(256) void knn_ei_gm_kernel(
    const float* __restrict__ eig, const float* __restrict__ PQR, int Mtot,
    const int* __restrict__ idx_eu, const float* __restrict__ g, const float* __restrict__ bb,
    float* __restrict__ xout){
  __shared__ float4 sp[N];
  __shared__ int sIei[4][KNB];
  int wave = threadIdx.x >> 6;
  gm_body<COUT,N>(eig, PQR, Mtot, idx_eu, g, bb, xout, blockIdx.x, blockIdx.y, sp, &sIei[wave][0]);
}

// fps2 (blocks 0..15) runs concurrently with gathermax2 (rest)
template<int COUT, int N, int M>
__global__ __launch_bounds__(256, 1) void gmfps_kernel(
    const float* __restrict__ eig, const float* __restrict__ ptsN,
    const float* __restrict__ PQR, int Mtot,
    const int* __restrict__ idx_eu, const float* __restrict__ g, const float* __restrict__ bb,
    float* __restrict__ xout, int* __restrict__ fps_id){
  __shared__ float4 sp[N];
  __shared__ int sIei[4][KNB];
  __shared__ unsigned long long rk[8];
  if (blockIdx.x < 16){
    fps_body4<N,M>(ptsN, fps_id, blockIdx.x, sp, rk);
    return;
  }
  int bx = blockIdx.x - 16;
  int wave = threadIdx.x >> 6;
  gm_body<COUT,N>(eig, PQR, Mtot, idx_eu, g, bb, xout, bx % (N/4), bx / (N/4), sp, &sIei[wave][0]);
}

// ---------------- gathers (consolidated) ----------------
__global__ __launch_bounds__(256) void gather2_kernel(const float* __restrict__ pts1, const float* __restrict__ x1,
                               const int* __restrict__ id2, float* __restrict__ pts2, float* __restrict__ x1d){
  int i = blockIdx.x*256 + threadIdx.x;
  if (i < 16*512){
    int b = i >> 9;
    int src = id2[i];
    const float* p = pts1 + ((size_t)b*1024 + src)*3;
    float* o = pts2 + (size_t)i*3;
    o[0]=p[0]; o[1]=p[1]; o[2]=p[2];
  } else {
    int e = i - 16*512;
    if (e < 16*512*64){
      int c = e & 63, r = e >> 6;
      int b = r >> 9, s = r & 511;
      int src = id2[(size_t)b*512 + s];
      x1d[e] = x1[((size_t)b*1024 + src)*64 + c];
    }
  }
}

__global__ __launch_bounds__(256) void gather3_kernel(const float* __restrict__ pts2, const float* __restrict__ x2,
                               const float* __restrict__ x1d, const int* __restrict__ id3,
                               float* __restrict__ pts3, float* __restrict__ x2d, float* __restrict__ x1dd){
  int i = blockIdx.x*256 + threadIdx.x;
  if (i < 16*256){
    int b = i >> 8;
    int src = id3[i];
    const float* p = pts2 + ((size_t)b*512 + src)*3;
    float* o = pts3 + (size_t)i*3;
    o[0]=p[0]; o[1]=p[1]; o[2]=p[2];
  } else {
    int e = i - 16*256;
    if (e < 16*256*64){
      int c = e & 63, r = e >> 6;
      int b = r >> 8, s = r & 255;
      int src = id3[(size_t)b*256 + s];
      x2d[e] = x2[((size_t)b*512 + src)*64 + c];
    } else {
      int e2 = e - 16*256*64;
      if (e2 < 16*256*64){
        int c = e2 & 63, r = e2 >> 6;
        int b = r >> 8, s = r & 255;
        int src = id3[(size_t)b*256 + s];
        x1dd[e2] = x1d[((size_t)b*512 + src)*64 + c];
      }
    }
  }
}

// ---------------- dense GEMM: PQR[set][m][o] = X[m][:] . Wc[set][o][:] ----------------
template<int COUT>
__global__ __launch_bounds__(256) void gemm_xw_kernel(
    const float* __restrict__ X, const float* __restrict__ Wc,
    float* __restrict__ PQR, int Mtot){
  __shared__ float sA[64][68];
  __shared__ float sW[64][68];
  int mt = blockIdx.x, ot = blockIdx.y, set = blockIdx.z;
  int t = threadIdx.x;
  for (int e=t; e<4096; e+=256){ int r=e>>6, c=e&63; sA[r][c] = X[(size_t)(mt*64+r)*64 + c]; }
  const float* Wp = Wc + ((size_t)set*COUT + ot*64)*64;
  for (int e=t; e<4096; e+=256){ int r=e>>6, c=e&63; sW[r][c] = Wp[(size_t)r*64 + c]; }
  __syncthreads();
  int tx = t & 15, ty = t >> 4;
  float acc[4][4];
  #pragma unroll
  for (int r=0;r<4;++r)
    #pragma unroll
    for (int j=0;j<4;++j) acc[r][j]=0.f;
  #pragma unroll
  for (int k4=0;k4<16;++k4){
    float4 A0 = *(const float4*)&sA[ty*4+0][k4*4];
    float4 A1 = *(const float4*)&sA[ty*4+1][k4*4];
    float4 A2 = *(const float4*)&sA[ty*4+2][k4*4];
    float4 A3 = *(const float4*)&sA[ty*4+3][k4*4];
    float4 W0 = *(const float4*)&sW[tx*4+0][k4*4];
    float4 W1 = *(const float4*)&sW[tx*4+1][k4*4];
    float4 W2 = *(const float4*)&sW[tx*4+2][k4*4];
    float4 W3 = *(const float4*)&sW[tx*4+3][k4*4];
    float4 A[4] = {A0,A1,A2,A3};
    float4 W[4] = {W0,W1,W2,W3};
    #pragma unroll
    for (int r=0;r<4;++r)
      #pragma unroll
      for (int j=0;j<4;++j){
        float s = acc[r][j];
        s = fmaf(A[r].x, W[j].x, s);
        s = fmaf(A[r].y, W[j].y, s);
        s = fmaf(A[r].z, W[j].z, s);
        s = fmaf(A[r].w, W[j].w, s);
        acc[r][j] = s;
      }
  }
  float* outp = PQR + (size_t)set*Mtot*COUT;
  #pragma unroll
  for (int r=0;r<4;++r){
    float4 v = make_float4(acc[r][0], acc[r][1], acc[r][2], acc[r][3]);
    *(float4*)&outp[(size_t)(mt*64 + ty*4 + r)*COUT + ot*64 + tx*4] = v;
  }
}

// ---------------- conv5 as tiled GEMM ----------------
__global__ __launch_bounds__(256) void conv5_gemm_kernel(
    const float* __restrict__ x1dd, const float* __restrict__ x2d, const float* __restrict__ x3,
    const float* __restrict__ w, const float* __restrict__ g, const float* __restrict__ bb,
    float* __restrict__ pmax, float* __restrict__ psum){
  __shared__ float sA[64][68];
  __shared__ float sB[64][68];
  int otile = blockIdx.x, ntile = blockIdx.y, b = blockIdx.z;
  int t = threadIdx.x;
  int tx = t & 15, ty = t >> 4;
  float acc[4][4];
  #pragma unroll
  for (int i=0;i<4;++i)
    #pragma unroll
    for (int j=0;j<4;++j) acc[i][j] = 0.f;
  for (int kc=0; kc<4; ++kc){
    #pragma unroll 4
    for (int e = t; e < 4096; e += 256){
      int nl = e >> 6, kl = e & 63;
      int n = ntile*64 + nl;
      float v;
      if (kc == 0)      v = x1dd[((size_t)b*256 + n)*64 + kl];
      else if (kc == 1) v = x2d [((size_t)b*256 + n)*64 + kl];
      else              v = x3  [((size_t)b*256 + n)*128 + (kc-2)*64 + kl];
      sA[nl][kl] = v;
    }
    #pragma unroll 4
    for (int e = t; e < 4096; e += 256){
      int ol = e >> 6, kl = e & 63;
      sB[ol][kl] = w[((size_t)(otile*64 + ol))*256 + kc*64 + kl];
    }
    __syncthreads();
    #pragma unroll
    for (int k4=0; k4<16; ++k4){
      float4 a0 = *(const float4*)&sA[ty*4+0][k4*4];
      float4 a1 = *(const float4*)&sA[ty*4+1][k4*4];
      float4 a2 = *(const float4*)&sA[ty*4+2][k4*4];
      float4 a3 = *(const float4*)&sA[ty*4+3][k4*4];
      float4 b0 = *(const float4*)&sB[tx*4+0][k4*4];
      float4 b1 = *(const float4*)&sB[tx*4+1][k4*4];
      float4 b2 = *(const float4*)&sB[tx*4+2][k4*4];
      float4 b3 = *(const float4*)&sB[tx*4+3][k4*4];
      float4 A[4] = {a0,a1,a2,a3};
      float4 Bv[4] = {b0,b1,b2,b3};
      #pragma unroll
      for (int i=0;i<4;++i)
        #pragma unroll
        for (int j=0;j<4;++j){
          float s = acc[i][j];
          s = fmaf(A[i].x, Bv[j].x, s);
          s = fmaf(A[i].y, Bv[j].y, s);
          s = fmaf(A[i].z, Bv[j].z, s);
          s = fmaf(A[i].w, Bv[j].w, s);
          acc[i][j] = s;
        }
    }
    __syncthreads();
  }
  float sg[4], sbv[4];
  #pragma unroll
  for (int j=0;j<4;++j){
    int o = otile*64 + tx*4 + j;
    sg[j] = BN_INV*g[o]; sbv[j] = bb[o];
  }
  float mx[4], sm[4];
  #pragma unroll
  for (int j=0;j<4;++j){ mx[j]=-INFINITY; sm[j]=0.f; }
  #pragma unroll
  for (int i=0;i<4;++i)
    #pragma unroll
    for (int j=0;j<4;++j){
      float vv = lrelu(fmaf(acc[i][j], sg[j], sbv[j]));
      mx[j] = fmaxf(mx[j], vv);
      sm[j] += vv;
    }
  float* redM = &sA[0][0];
  float* redS = redM + 16*64;
  #pragma unroll
  for (int j=0;j<4;++j){
    redM[ty*64 + tx*4 + j] = mx[j];
    redS[ty*64 + tx*4 + j] = sm[j];
  }
  __syncthreads();
  if (t < 64){
    float m = -INFINITY, s = 0.f;
    #pragma unroll
    for (int r=0;r<16;++r){
      m = fmaxf(m, redM[r*64 + t]);
      s += redS[r*64 + t];
    }
    int o = otile*64 + t;
    pmax[((size_t)b*1024 + o)*4 + ntile] = m;
    psum[((size_t)b*1024 + o)*4 + ntile] = s;
  }
}

// ---------------- lin1 (head_reduce fused in) ----------------
__global__ __launch_bounds__(256) void lin1_kernel(const float* __restrict__ pmax, const float* __restrict__ psum,
    const float* __restrict__ w, const float* __restrict__ g, const float* __restrict__ bb,
    float* __restrict__ y1){
  __shared__ float sh[2048];
  int b = blockIdx.y; int o = blockIdx.x*256 + threadIdx.x;
  for (int e=threadIdx.x; e<2048; e+=256){
    if (e < 1024){
      const float* pm = pmax + ((size_t)b*1024 + e)*4;
      sh[e] = fmaxf(fmaxf(pm[0],pm[1]), fmaxf(pm[2],pm[3]));
    } else {
      const float* ps = psum + ((size_t)b*1024 + (e-1024))*4;
      sh[e] = ((ps[0]+ps[1])+(ps[2]+ps[3])) * (1.0f/256.0f);
    }
  }
  __syncthreads();
  const float* wr = w + (size_t)o*2048;
  float acc=0.f;
  for (int c=0;c<2048;++c) acc = fmaf(wr[c], sh[c], acc);
  y1[(size_t)b*512+o] = lrelu(fmaf(acc, BN_INV*g[o], bb[o]));
}

// ---------------- lin2 + lin3 fused (y2 stays in LDS) ----------------
__global__ __launch_bounds__(256) void lin23_kernel(const float* __restrict__ y1,
    const float* __restrict__ w2, const float* __restrict__ lb2,
    const float* __restrict__ g, const float* __restrict__ bb,
    const float* __restrict__ w3, const float* __restrict__ lb3,
    float* __restrict__ outp){
  __shared__ float sh1[512];
  __shared__ float sh2[256];
  int b = blockIdx.x; int o = threadIdx.x;
  for (int e=o; e<512; e+=256) sh1[e]=y1[(size_t)b*512+e];
  __syncthreads();
  {
    const float* wr = w2 + (size_t)o*512;
    float acc=0.f;
    for (int c=0;c<512;++c) acc = fmaf(wr[c], sh1[c], acc);
    acc += lb2[o];
    sh2[o] = lrelu(fmaf(acc, BN_INV*g[o], bb[o]));
  }
  __syncthreads();
  if (o < 40){
    const float* wr = w3 + (size_t)o*256;
    float acc=0.f;
    for (int c=0;c<256;++c) acc = fmaf(wr[c], sh2[c], acc);
    outp[(size_t)b*40+o] = acc + lb3[o];
  }
}

extern "C" void kernel_launch(void* const* d_in, const int* in_sizes, int n_in,
                              void* d_out, int out_size, void* d_ws, size_t ws_size,
                              hipStream_t stream) {
  const float* x      = (const float*)d_in[0];
  const float* conv1w = (const float*)d_in[1];
  const float* bn1g   = (const float*)d_in[2];
  const float* bn1b   = (const float*)d_in[3];
  const float* conv2w = (const float*)d_in[4];
  const float* bn2g   = (const float*)d_in[5];
  const float* bn2b   = (const float*)d_in[6];
  const float* conv3w = (const float*)d_in[7];
  const float* bn3g   = (const float*)d_in[8];
  const float* bn3b   = (const float*)d_in[9];
  const float* conv5w = (const float*)d_in[10];
  const float* bn5g   = (const float*)d_in[11];
  const float* bn5b   = (const float*)d_in[12];
  const float* lin1w  = (const float*)d_in[13];
  const float* bn6g   = (const float*)d_in[14];
  const float* bn6b   = (const float*)d_in[15];
  const float* lin2w  = (const float*)d_in[16];
  const float* lin2b  = (const float*)d_in[17];
  const float* bn7g   = (const float*)d_in[18];
  const float* bn7b   = (const float*)d_in[19];
  const float* lin3w  = (const float*)d_in[20];
  const float* lin3b  = (const float*)d_in[21];
  float* outp = (float*)d_out;

  char* ws = (char*)d_ws;
  size_t off = 0;
  auto alloc = [&](size_t bytes)->char*{
    off = (off + 255) & ~(size_t)255;
    char* p = ws + off; off += bytes; return p;
  };
  const int B=16, N1=1024, N2=512, N3=256;
  float* pts1 = (float*)alloc((size_t)B*N1*3*4);
  int*   ieu1 = (int*)alloc((size_t)B*N1*KNB*4);
  float* eig1 = (float*)alloc((size_t)B*N1*3*4);
  float* x1   = (float*)alloc((size_t)B*N1*64*4);
  int*   id2  = (int*)alloc((size_t)B*N2*4);
  float* pts2 = (float*)alloc((size_t)B*N2*3*4);
  float* x1d  = (float*)alloc((size_t)B*N2*64*4);
  int*   ieu2 = (int*)alloc((size_t)B*N2*KNB*4);
  float* eig2 = (float*)alloc((size_t)B*N2*3*4);
  float* x2   = (float*)alloc((size_t)B*N2*64*4);
  int*   id3  = (int*)alloc((size_t)B*N3*4);
  float* pts3 = (float*)alloc((size_t)B*N3*3*4);
  float* x2d  = (float*)alloc((size_t)B*N3*64*4);
  float* x1dd = (float*)alloc((size_t)B*N3*64*4);
  int*   ieu3 = (int*)alloc((size_t)B*N3*KNB*4);
  float* eig3 = (float*)alloc((size_t)B*N3*3*4);
  float* x3   = (float*)alloc((size_t)B*N3*128*4);
  float* pmax = (float*)alloc((size_t)B*1024*4*4);
  float* psum = (float*)alloc((size_t)B*1024*4*4);
  float* y1   = (float*)alloc((size_t)B*512*4);
  float* Wc2  = (float*)alloc((size_t)3*64*64*4);
  float* Wc3  = (float*)alloc((size_t)3*128*64*4);
  float* PQR2 = (float*)alloc((size_t)3*B*N2*64*4);
  float* PQR3 = (float*)alloc((size_t)3*B*N3*128*4);

  prep_kernel<<<112, 256, 0, stream>>>(x, pts1, conv2w, Wc2, conv3w, Wc3);
  knn_cov_kernel<1024,4><<<dim3(64,16), 256, 0, stream>>>(pts1, ieu1, eig1);
  // fps1 || (knn_ei1 + stage1)
  mega1_kernel<<<16 + 4096, 256, 0, stream>>>(pts1, id2, eig1, ieu1, conv1w, bn1g, bn1b, x1);
  gather2_kernel<<<2080, 256, 0, stream>>>(pts1, x1, id2, pts2, x1d);
  gemm_xw_kernel<64><<<dim3(128, 1, 3), 256, 0, stream>>>(x1d, Wc2, PQR2, B*N2);
  knn_cov_kernel<512,2><<<dim3(64,16), 256, 0, stream>>>(pts2, ieu2, eig2);
  // fps2 || gathermax2
  gmfps_kernel<64,512,256><<<16 + 2048, 256, 0, stream>>>(eig2, pts2, PQR2, B*N2, ieu2, bn2g, bn2b, x2, id3);
  gather3_kernel<<<2064, 256, 0, stream>>>(pts2, x2, x1d, id3, pts3, x2d, x1dd);
  gemm_xw_kernel<128><<<dim3(64, 2, 3), 256, 0, stream>>>(x2d, Wc3, PQR3, B*N3);
  knn_cov_kernel<256,1><<<dim3(64,16), 256, 0, stream>>>(pts3, ieu3, eig3);
  knn_ei_gm_kernel<128,256><<<dim3(64,16), 256, 0, stream>>>(eig3, PQR3, B*N3, ieu3, bn3g, bn3b, x3);
  conv5_gemm_kernel<<<dim3(16,4,16), 256, 0, stream>>>(x1dd, x2d, x3, conv5w, bn5g, bn5b, pmax, psum);
  lin1_kernel<<<dim3(2,16), 256, 0, stream>>>(pmax, psum, lin1w, bn6g, bn6b, y1);
  lin23_kernel<<<16, 256, 0, stream>>>(y1, lin2w, lin2b, bn7g, bn7b, lin3w, lin3b, outp);
}

// Round 18
// 598.202 us; speedup vs baseline: 1.1066x; 1.1066x over previous
//
#include <hip/hip_runtime.h>
#include <math.h>

#define KNB 20
constexpr float BN_INV = 0.9999950000374997f;  // 1/sqrt(1+1e-5)
constexpr float SLOPE = 0.2f;

__device__ __forceinline__ float lrelu(float v){ return v >= 0.f ? v : SLOPE*v; }

#define DPPMAX(ctrl) { unsigned lo=(unsigned)bk, hi=(unsigned)(bk>>32); \
  unsigned lo2=(unsigned)__builtin_amdgcn_mov_dpp((int)lo, ctrl, 0xF, 0xF, true); \
  unsigned hi2=(unsigned)__builtin_amdgcn_mov_dpp((int)hi, ctrl, 0xF, 0xF, true); \
  unsigned long long ok=((unsigned long long)hi2<<32)|lo2; if(ok>bk)bk=ok; }

__device__ __forceinline__ unsigned long long wave_max64_all(unsigned long long bk){
  DPPMAX(0xB1) DPPMAX(0x4E) DPPMAX(0x124) DPPMAX(0x128)
  { unsigned long long ok = __shfl_xor(bk, 16); if (ok > bk) bk = ok; }
  { unsigned long long ok = __shfl_xor(bk, 32); if (ok > bk) bk = ok; }
  return bk;
}

// ---------------- prep: transpose x + combine conv2/conv3 weights ----------------
__global__ __launch_bounds__(256) void prep_kernel(const float* __restrict__ x, float* __restrict__ pts,
                            const float* __restrict__ conv2w, float* __restrict__ Wc2,
                            const float* __restrict__ conv3w, float* __restrict__ Wc3){
  int i = blockIdx.x*256 + threadIdx.x;
  if (i < 16*1024){
    int b = i >> 10, n = i & 1023;
    const float* xb = x + (size_t)b*3*1024;
    float* p = pts + (size_t)i*3;
    p[0]=xb[n]; p[1]=xb[1024+n]; p[2]=xb[2048+n];
  } else if (i < 16*1024 + 64*64){
    int e = i - 16*1024;
    int o = e >> 6, c = e & 63;
    float wa=conv2w[(size_t)o*256+c], wb=conv2w[(size_t)o*256+64+c];
    float wc=conv2w[(size_t)o*256+128+c], wd=conv2w[(size_t)o*256+192+c];
    Wc2[((size_t)0*64+o)*64+c]=wa+wb; Wc2[((size_t)1*64+o)*64+c]=wc+wd; Wc2[((size_t)2*64+o)*64+c]=wa+wc;
  } else if (i < 16*1024 + 64*64 + 128*64){
    int e = i - 16*1024 - 64*64;
    int o = e >> 6, c = e & 63;
    float wa=conv3w[(size_t)o*256+c], wb=conv3w[(size_t)o*256+64+c];
    float wc=conv3w[(size_t)o*256+128+c], wd=conv3w[(size_t)o*256+192+c];
    Wc3[((size_t)0*128+o)*64+c]=wa+wb; Wc3[((size_t)1*128+o)*64+c]=wc+wd; Wc3[((size_t)2*128+o)*64+c]=wa+wc;
  }
}

// ---------------- kNN core (float path): one wave per query row ----------------
template<int N, bool TOGLOBAL>
__device__ void knn_core(const float* __restrict__ pts, int* __restrict__ idx_global,
                         int* __restrict__ sOut, int chunk, int b, float4* sp){
#pragma clang fp contract(off)
  constexpr int E = N/64;
  int t = threadIdx.x;
  const float* pb = pts + (size_t)b*N*3;
  for (int e = t; e < N; e += 256){
    float x0=pb[e*3], x1=pb[e*3+1], x2=pb[e*3+2];
    sp[e] = make_float4(x0, x1, x2, (x0*x0 + x1*x1) + x2*x2);
  }
  __syncthreads();
  int wave = t >> 6, lane = t & 63;
  int row = chunk*4 + wave;
  float4 P = sp[row];
  float nd[E];
  #pragma unroll
  for (int i=0;i<E;++i){
    float4 Q = sp[lane + i*64];
    float inner = (P.x*Q.x + P.y*Q.y) + P.z*Q.z;
    nd[i] = (2.0f*inner - P.w) - Q.w;
  }
  int myout = 0;
  for (int j=0;j<KNB;++j){
    float bv = nd[0]; int bi = lane;
    #pragma unroll
    for (int i=1;i<E;++i){
      if (nd[i] > bv){ bv = nd[i]; bi = lane + i*64; }
    }
    #pragma unroll
    for (int off=1; off<64; off<<=1){
      float ov = __shfl_xor(bv, off);
      int oi = __shfl_xor(bi, off);
      if (ov > bv || (ov == bv && oi < bi)){ bv = ov; bi = oi; }
    }
    if (lane == j) myout = bi;
    if (lane == (bi & 63)){
      int slot = bi >> 6;
      #pragma unroll
      for (int i=0;i<E;++i) if (i == slot) nd[i] = -INFINITY;
    }
  }
  if (TOGLOBAL){
    if (lane < KNB) idx_global[((size_t)b*N + row)*KNB + lane] = myout;
  } else {
    if (lane < KNB) sOut[lane] = myout;
  }
}

template<int N>
__global__ __launch_bounds__(256) void knn_kernel(const float* __restrict__ pts, int* __restrict__ idx){
  __shared__ float4 sp[N];
  knn_core<N,true>(pts, idx, nullptr, blockIdx.x, blockIdx.y, sp);
}

// ---------------- kNN core (u64/DPP path) — used only inside mega1 (fps-co-resident) ----------------
template<int N>
__device__ void knn_core64(const float* __restrict__ pts, int* __restrict__ sOut,
                           int chunk, int b, float4* sp){
#pragma clang fp contract(off)
  constexpr int E = N/64;
  int t = threadIdx.x;
  const float* pb = pts + (size_t)b*N*3;
  for (int e = t; e < N; e += 256){
    float x0=pb[e*3], x1=pb[e*3+1], x2=pb[e*3+2];
    sp[e] = make_float4(x0, x1, x2, (x0*x0 + x1*x1) + x2*x2);
  }
  __syncthreads();
  int wave = t >> 6, lane = t & 63;
  int row = chunk*4 + wave;
  float4 P = sp[row];
  unsigned long long key[E];
  #pragma unroll
  for (int i=0;i<E;++i){
    float4 Q = sp[lane + i*64];
    float inner = (P.x*Q.x + P.y*Q.y) + P.z*Q.z;
    float nd = (2.0f*inner - P.w) - Q.w;
    unsigned u = __float_as_uint(nd);
    u ^= ((unsigned)((int)u >> 31)) | 0x80000000u;   // monotone order-embed
    key[i] = ((unsigned long long)u << 32) | (unsigned)(~(lane + i*64));
  }
  int myout = 0;
  for (int j=0;j<KNB;++j){
    unsigned long long best = key[0];
    #pragma unroll
    for (int i=1;i<E;++i) best = key[i] > best ? key[i] : best;
    best = wave_max64_all(best);
    int wid = (int)(~(unsigned)best);
    if (lane == j) myout = wid;
    if (lane == (wid & 63)){
      int slot = wid >> 6;
      #pragma unroll
      for (int i=0;i<E;++i) if (i == slot) key[i] = 0ULL;
    }
  }
  if (lane < KNB) sOut[lane] = myout;
}

// ---------------- FPS v5: 4-wave split, u64 keys, key-only all-DPP butterfly ----------------
#define DECLQ4(i) float4 Q##i = sp[(i)*256 + tid]; float D##i = 1e10f; \
  asm volatile("" : "+v"(Q##i.x), "+v"(Q##i.y), "+v"(Q##i.z));
#define UPD4(i, B) { float dx=Q##i.x-L.x; float dy=Q##i.y-L.y; float dz=Q##i.z-L.z; \
  float dd=fminf(D##i,(dx*dx+dy*dy)+dz*dz); D##i=dd; \
  unsigned long long k=((unsigned long long)__float_as_uint(dd)<<32)|(unsigned long long)(nl-(unsigned)((i)*256)); \
  if(k>B)B=k; }
#define FPS_STEP_TAIL \
      DPPMAX(0xB1) DPPMAX(0x4E) DPPMAX(0x124) DPPMAX(0x128) DPPMAX(0x142) DPPMAX(0x143) \
      if (lane == 63) rk[((s&1)<<2) | w] = bk; \
      __syncthreads(); \
      { const unsigned long long* rp = rk + ((s&1)<<2); \
        unsigned long long k0=rp[0], k1=rp[1], k2=rp[2], k3=rp[3]; \
        unsigned long long km1 = k0>k1?k0:k1, km2 = k2>k3?k2:k3; \
        unsigned long long kk = km1>km2?km1:km2; \
        last = (int)(~(unsigned int)kk); } \
      if (tid==0) idout[(size_t)b*M + s] = last;

template<int N, int M>
__device__ void fps_body4(const float* __restrict__ pts, int* __restrict__ idout,
                          int b, float4* sp, unsigned long long* rk){
#pragma clang fp contract(off)
  constexpr int E4 = N/256;
  int tid = threadIdx.x;
  const float* pb = pts + (size_t)b*N*3;
  for (int e=tid; e<N; e+=256){
    sp[e] = make_float4(pb[e*3], pb[e*3+1], pb[e*3+2], 0.f);
  }
  __syncthreads();
  __builtin_amdgcn_s_setprio(1);
  int lane = tid & 63, w = tid >> 6;
  unsigned int nl = ~(unsigned int)tid;
  int last = 0;
  if (tid==0) idout[(size_t)b*M] = 0;
  if constexpr (E4 == 4){
    DECLQ4(0) DECLQ4(1) DECLQ4(2) DECLQ4(3)
    for (int s=1; s<M; ++s){
      float4 L = sp[last];
      unsigned long long b0=0ULL,b1=0ULL,b2=0ULL,b3=0ULL;
      UPD4(0,b0) UPD4(1,b1) UPD4(2,b2) UPD4(3,b3)
      unsigned long long kl_ = b0>b1?b0:b1, kh_ = b2>b3?b2:b3;
      unsigned long long bk = kl_>kh_?kl_:kh_;
      FPS_STEP_TAIL
    }
  } else {
    DECLQ4(0) DECLQ4(1)
    for (int s=1; s<M; ++s){
      float4 L = sp[last];
      unsigned long long b0=0ULL,b1=0ULL;
      UPD4(0,b0) UPD4(1,b1)
      unsigned long long bk = b0>b1?b0:b1;
      FPS_STEP_TAIL
    }
  }
}

// ---------------- covariance + analytic 3x3 symmetric eigenvalues ----------------
template<int N>
__global__ void cov_eig_kernel(const float* __restrict__ pts, const int* __restrict__ idx,
                               float* __restrict__ eigval){
  int i = blockIdx.x*blockDim.x + threadIdx.x;
  if (i >= 16*N) return;
  int b = i / N, n = i % N;
  const float* pb = pts + (size_t)b*N*3;
  const int* ix = idx + (size_t)i*KNB;
  float cx = pb[n*3], cy = pb[n*3+1], cz = pb[n*3+2];
  float c00=0,c01=0,c02=0,c11=0,c12=0,c22=0;
  for (int k=0;k<KNB;++k){
    int m = ix[k];
    float dx = pb[m*3]-cx, dy = pb[m*3+1]-cy, dz = pb[m*3+2]-cz;
    c00 += dx*dx; c01 += dx*dy; c02 += dx*dz;
    c11 += dy*dy; c12 += dy*dz; c22 += dz*dz;
  }
  double a00=c00,a01=c01,a02=c02,a11=c11,a12=c12,a22=c22;
  double p1 = a01*a01 + a02*a02 + a12*a12;
  double q = (a00+a11+a22)/3.0;
  double b00=a00-q, b11=a11-q, b22=a22-q;
  double p2 = b00*b00+b11*b11+b22*b22 + 2.0*p1;
  double e0,e1,e2;
  if (p2 <= 0.0){
    e0=e1=e2=q;
  } else {
    double p = sqrt(p2/6.0);
    double det = b00*(b11*b22 - a12*a12) - a01*(a01*b22 - a12*a02) + a02*(a01*a12 - b11*a02);
    double r = det / (2.0*p*p*p);
    r = fmin(1.0, fmax(-1.0, r));
    double phi = acos(r)/3.0;
    double big = q + 2.0*p*cos(phi);
    double sml = q + 2.0*p*cos(phi + 2.0943951023931953);
    double mid = 3.0*q - big - sml;
    e0 = sml; e1 = mid; e2 = big;
  }
  float* ev = eigval + (size_t)i*3;
  ev[0]=(float)e0; ev[1]=(float)e1; ev[2]=(float)e2;
}

// ---------------- stage1 body: kNN64(eig1) + 13-ch feat + conv1 + BN + lrelu + max_k ----------------
__device__ void stage1_body(
    const float* __restrict__ eig, const float* __restrict__ pts,
    const int* __restrict__ idx_eu,
    const float* __restrict__ w, const float* __restrict__ g, const float* __restrict__ bb,
    float* __restrict__ x1, int chunk, int b,
    float4* sp, int (*sIei)[KNB], float (*feat)[13][KNB]){
  constexpr int N = 1024;
  int t = threadIdx.x, wave = t>>6, lane = t&63;
  knn_core64<N>(eig, &sIei[wave][0], chunk, b, sp);
  int row = chunk*4 + wave;
  size_t i = (size_t)b*N + row;
  const float* pb = pts + (size_t)b*N*3;
  if (lane < KNB){
    int ieu = idx_eu[i*KNB + lane];
    int iei = sIei[wave][lane];
    float4 ne4 = sp[iei];
    float4 ee4 = sp[row];
    float d2 = 0.f;
    #pragma unroll
    for (int f=0; f<3; ++f){
      float nx = pb[ieu*3+f], xx = pb[row*3+f];
      float dfv = nx - xx;
      feat[wave][f][lane] = dfv; feat[wave][3+f][lane] = nx;
      float ne = (f==0)? ne4.x : ((f==1)? ne4.y : ne4.z);
      float ee = (f==0)? ee4.x : ((f==1)? ee4.y : ee4.z);
      feat[wave][6+f][lane] = ne - ee; feat[wave][9+f][lane] = ne;
      d2 += dfv*dfv;
    }
    feat[wave][12][lane] = sqrtf(fmaxf(d2, 1e-12f));
  }
  __syncthreads();
  float wr[13];
  #pragma unroll
  for (int c=0;c<13;++c) wr[c] = w[lane*13+c];
  float sg = BN_INV * g[lane], sb = bb[lane];
  float mx = -INFINITY;
  for (int k=0;k<KNB;++k){
    float s = 0.f;
    #pragma unroll
    for (int c=0;c<13;++c) s = fmaf(wr[c], feat[wave][c][k], s);
    mx = fmaxf(mx, lrelu(fmaf(s, sg, sb)));
  }
  x1[i*64 + lane] = mx;
}

// ---------------- mega1: fps1 (blocks 0..15) || knn_ei+stage1 (rest) ----------------
__global__ __launch_bounds__(256, 1) void mega1_kernel(
    const float* __restrict__ pts1, int* __restrict__ fps_id,
    const float* __restrict__ eig1, const int* __restrict__ idx_eu,
    const float* __restrict__ w, const float* __restrict__ g, const float* __restrict__ bb,
    float* __restrict__ x1){
  __shared__ float4 sp[1024];
  __shared__ int sIei[4][KNB];
  __shared__ float feat[4][13][KNB];
  __shared__ unsigned long long rk[8];
  if (blockIdx.x < 16){
    fps_body4<1024,512>(pts1, fps_id, blockIdx.x, sp, rk);
  } else {
    int bx = blockIdx.x - 16;
    stage1_body(eig1, pts1, idx_eu, w, g, bb, x1, bx & 255, bx >> 8, sp, sIei, feat);
  }
}

// ---------------- fused: kNN(eig) + gathermax ----------------
template<int COUT, int N>
__device__ void gm_body(const float* __restrict__ eig,
    const float* __restrict__ PQR, int Mtot,
    const int* __restrict__ idx_eu,
    const float* __restrict__ g, const float* __restrict__ bb,
    float* __restrict__ xout, int chunk, int b, float4* sp, int* sIeiW){
  int t = threadIdx.x, wave = t>>6, lane = t&63;
  knn_core<N,false>(eig, nullptr, sIeiW, chunk, b, sp);
  __syncthreads();
  int row = chunk*4 + wave;
  size_t i = (size_t)b*N + row;
  const float* P = PQR;
  const float* Q = PQR + (size_t)Mtot*COUT;
  const float* R = PQR + (size_t)2*Mtot*COUT;
  for (int o = lane; o < COUT; o += 64){
    float base = R[i*COUT + o];
    float sg = BN_INV*g[o], sb = bb[o];
    float mx = -INFINITY;
    for (int k=0;k<KNB;++k){
      int eu = idx_eu[i*KNB + k];
      int ei = sIeiW[k];
      float v = P[((size_t)b*N + eu)*COUT + o] + Q[((size_t)b*N + ei)*COUT + o] - base;
      mx = fmaxf(mx, lrelu(fmaf(v, sg, sb)));
    }
    xout[i*COUT + o] = mx;
  }
}

template<int COUT, int N>
__global__ __launch_bounds__(256) void knn_ei_gm_kernel(
    const float* __restrict__ eig, const float* __restrict__ PQR, int Mtot,
    const int* __restrict__ idx_eu, const float* __restrict__ g, const float* __restrict__ bb,
    float* __restrict__ xout){
  __shared__ float4 sp[N];
  __shared__ int sIei[4][KNB];
  int wave = threadIdx.x >> 6;
  gm_body<COUT,N>(eig, PQR, Mtot, idx_eu, g, bb, xout, blockIdx.x, blockIdx.y, sp, &sIei[wave][0]);
}

// fps2 (blocks 0..15) runs concurrently with gathermax2 (rest)
template<int COUT, int N, int M>
__global__ __launch_bounds__(256, 1) void gmfps_kernel(
    const float* __restrict__ eig, const float* __restrict__ ptsN,
    const float* __restrict__ PQR, int Mtot,
    const int* __restrict__ idx_eu, const float* __restrict__ g, const float* __restrict__ bb,
    float* __restrict__ xout, int* __restrict__ fps_id){
  __shared__ float4 sp[N];
  __shared__ int sIei[4][KNB];
  __shared__ unsigned long long rk[8];
  if (blockIdx.x < 16){
    fps_body4<N,M>(ptsN, fps_id, blockIdx.x, sp, rk);
    return;
  }
  int bx = blockIdx.x - 16;
  int wave = threadIdx.x >> 6;
  gm_body<COUT,N>(eig, PQR, Mtot, idx_eu, g, bb, xout, bx % (N/4), bx / (N/4), sp, &sIei[wave][0]);
}

// ---------------- gathers (consolidated) ----------------
__global__ __launch_bounds__(256) void gather2_kernel(const float* __restrict__ pts1, const float* __restrict__ x1,
                               const int* __restrict__ id2, float* __restrict__ pts2, float* __restrict__ x1d){
  int i = blockIdx.x*256 + threadIdx.x;
  if (i < 16*512){
    int b = i >> 9;
    int src = id2[i];
    const float* p = pts1 + ((size_t)b*1024 + src)*3;
    float* o = pts2 + (size_t)i*3;
    o[0]=p[0]; o[1]=p[1]; o[2]=p[2];
  } else {
    int e = i - 16*512;
    if (e < 16*512*64){
      int c = e & 63, r = e >> 6;
      int b = r >> 9, s = r & 511;
      int src = id2[(size_t)b*512 + s];
      x1d[e] = x1[((size_t)b*1024 + src)*64 + c];
    }
  }
}

__global__ __launch_bounds__(256) void gather3_kernel(const float* __restrict__ pts2, const float* __restrict__ x2,
                               const float* __restrict__ x1d, const int* __restrict__ id3,
                               float* __restrict__ pts3, float* __restrict__ x2d, float* __restrict__ x1dd){
  int i = blockIdx.x*256 + threadIdx.x;
  if (i < 16*256){
    int b = i >> 8;
    int src = id3[i];
    const float* p = pts2 + ((size_t)b*512 + src)*3;
    float* o = pts3 + (size_t)i*3;
    o[0]=p[0]; o[1]=p[1]; o[2]=p[2];
  } else {
    int e = i - 16*256;
    if (e < 16*256*64){
      int c = e & 63, r = e >> 6;
      int b = r >> 8, s = r & 255;
      int src = id3[(size_t)b*256 + s];
      x2d[e] = x2[((size_t)b*512 + src)*64 + c];
    } else {
      int e2 = e - 16*256*64;
      if (e2 < 16*256*64){
        int c = e2 & 63, r = e2 >> 6;
        int b = r >> 8, s = r & 255;
        int src = id3[(size_t)b*256 + s];
        x1dd[e2] = x1d[((size_t)b*512 + src)*64 + c];
      }
    }
  }
}

// ---------------- dense GEMM: PQR[set][m][o] = X[m][:] . Wc[set][o][:] ----------------
template<int COUT>
__global__ __launch_bounds__(256) void gemm_xw_kernel(
    const float* __restrict__ X, const float* __restrict__ Wc,
    float* __restrict__ PQR, int Mtot){
  __shared__ float sA[64][68];
  __shared__ float sW[64][68];
  int mt = blockIdx.x, ot = blockIdx.y, set = blockIdx.z;
  int t = threadIdx.x;
  for (int e=t; e<4096; e+=256){ int r=e>>6, c=e&63; sA[r][c] = X[(size_t)(mt*64+r)*64 + c]; }
  const float* Wp = Wc + ((size_t)set*COUT + ot*64)*64;
  for (int e=t; e<4096; e+=256){ int r=e>>6, c=e&63; sW[r][c] = Wp[(size_t)r*64 + c]; }
  __syncthreads();
  int tx = t & 15, ty = t >> 4;
  float acc[4][4];
  #pragma unroll
  for (int r=0;r<4;++r)
    #pragma unroll
    for (int j=0;j<4;++j) acc[r][j]=0.f;
  #pragma unroll
  for (int k4=0;k4<16;++k4){
    float4 A0 = *(const float4*)&sA[ty*4+0][k4*4];
    float4 A1 = *(const float4*)&sA[ty*4+1][k4*4];
    float4 A2 = *(const float4*)&sA[ty*4+2][k4*4];
    float4 A3 = *(const float4*)&sA[ty*4+3][k4*4];
    float4 W0 = *(const float4*)&sW[tx*4+0][k4*4];
    float4 W1 = *(const float4*)&sW[tx*4+1][k4*4];
    float4 W2 = *(const float4*)&sW[tx*4+2][k4*4];
    float4 W3 = *(const float4*)&sW[tx*4+3][k4*4];
    float4 A[4] = {A0,A1,A2,A3};
    float4 W[4] = {W0,W1,W2,W3};
    #pragma unroll
    for (int r=0;r<4;++r)
      #pragma unroll
      for (int j=0;j<4;++j){
        float s = acc[r][j];
        s = fmaf(A[r].x, W[j].x, s);
        s = fmaf(A[r].y, W[j].y, s);
        s = fmaf(A[r].z, W[j].z, s);
        s = fmaf(A[r].w, W[j].w, s);
        acc[r][j] = s;
      }
  }
  float* outp = PQR + (size_t)set*Mtot*COUT;
  #pragma unroll
  for (int r=0;r<4;++r){
    float4 v = make_float4(acc[r][0], acc[r][1], acc[r][2], acc[r][3]);
    *(float4*)&outp[(size_t)(mt*64 + ty*4 + r)*COUT + ot*64 + tx*4] = v;
  }
}

// ---------------- conv5 as tiled GEMM ----------------
__global__ __launch_bounds__(256) void conv5_gemm_kernel(
    const float* __restrict__ x1dd, const float* __restrict__ x2d, const float* __restrict__ x3,
    const float* __restrict__ w, const float* __restrict__ g, const float* __restrict__ bb,
    float* __restrict__ pmax, float* __restrict__ psum){
  __shared__ float sA[64][68];
  __shared__ float sB[64][68];
  int otile = blockIdx.x, ntile = blockIdx.y, b = blockIdx.z;
  int t = threadIdx.x;
  int tx = t & 15, ty = t >> 4;
  float acc[4][4];
  #pragma unroll
  for (int i=0;i<4;++i)
    #pragma unroll
    for (int j=0;j<4;++j) acc[i][j] = 0.f;
  for (int kc=0; kc<4; ++kc){
    #pragma unroll 4
    for (int e = t; e < 4096; e += 256){
      int nl = e >> 6, kl = e & 63;
      int n = ntile*64 + nl;
      float v;
      if (kc == 0)      v = x1dd[((size_t)b*256 + n)*64 + kl];
      else if (kc == 1) v = x2d [((size_t)b*256 + n)*64 + kl];
      else              v = x3  [((size_t)b*256 + n)*128 + (kc-2)*64 + kl];
      sA[nl][kl] = v;
    }
    #pragma unroll 4
    for (int e = t; e < 4096; e += 256){
      int ol = e >> 6, kl = e & 63;
      sB[ol][kl] = w[((size_t)(otile*64 + ol))*256 + kc*64 + kl];
    }
    __syncthreads();
    #pragma unroll
    for (int k4=0; k4<16; ++k4){
      float4 a0 = *(const float4*)&sA[ty*4+0][k4*4];
      float4 a1 = *(const float4*)&sA[ty*4+1][k4*4];
      float4 a2 = *(const float4*)&sA[ty*4+2][k4*4];
      float4 a3 = *(const float4*)&sA[ty*4+3][k4*4];
      float4 b0 = *(const float4*)&sB[tx*4+0][k4*4];
      float4 b1 = *(const float4*)&sB[tx*4+1][k4*4];
      float4 b2 = *(const float4*)&sB[tx*4+2][k4*4];
      float4 b3 = *(const float4*)&sB[tx*4+3][k4*4];
      float4 A[4] = {a0,a1,a2,a3};
      float4 Bv[4] = {b0,b1,b2,b3};
      #pragma unroll
      for (int i=0;i<4;++i)
        #pragma unroll
        for (int j=0;j<4;++j){
          float s = acc[i][j];
          s = fmaf(A[i].x, Bv[j].x, s);
          s = fmaf(A[i].y, Bv[j].y, s);
          s = fmaf(A[i].z, Bv[j].z, s);
          s = fmaf(A[i].w, Bv[j].w, s);
          acc[i][j] = s;
        }
    }
    __syncthreads();
  }
  float sg[4], sbv[4];
  #pragma unroll
  for (int j=0;j<4;++j){
    int o = otile*64 + tx*4 + j;
    sg[j] = BN_INV*g[o]; sbv[j] = bb[o];
  }
  float mx[4], sm[4];
  #pragma unroll
  for (int j=0;j<4;++j){ mx[j]=-INFINITY; sm[j]=0.f; }
  #pragma unroll
  for (int i=0;i<4;++i)
    #pragma unroll
    for (int j=0;j<4;++j){
      float vv = lrelu(fmaf(acc[i][j], sg[j], sbv[j]));
      mx[j] = fmaxf(mx[j], vv);
      sm[j] += vv;
    }
  float* redM = &sA[0][0];
  float* redS = redM + 16*64;
  #pragma unroll
  for (int j=0;j<4;++j){
    redM[ty*64 + tx*4 + j] = mx[j];
    redS[ty*64 + tx*4 + j] = sm[j];
  }
  __syncthreads();
  if (t < 64){
    float m = -INFINITY, s = 0.f;
    #pragma unroll
    for (int r=0;r<16;++r){
      m = fmaxf(m, redM[r*64 + t]);
      s += redS[r*64 + t];
    }
    int o = otile*64 + t;
    pmax[((size_t)b*1024 + o)*4 + ntile] = m;
    psum[((size_t)b*1024 + o)*4 + ntile] = s;
  }
}

// ---------------- lin1 (head_reduce fused in) ----------------
__global__ __launch_bounds__(256) void lin1_kernel(const float* __restrict__ pmax, const float* __restrict__ psum,
    const float* __restrict__ w, const float* __restrict__ g, const float* __restrict__ bb,
    float* __restrict__ y1){
  __shared__ float sh[2048];
  int b = blockIdx.y; int o = blockIdx.x*256 + threadIdx.x;
  for (int e=threadIdx.x; e<2048; e+=256){
    if (e < 1024){
      const float* pm = pmax + ((size_t)b*1024 + e)*4;
      sh[e] = fmaxf(fmaxf(pm[0],pm[1]), fmaxf(pm[2],pm[3]));
    } else {
      const float* ps = psum + ((size_t)b*1024 + (e-1024))*4;
      sh[e] = ((ps[0]+ps[1])+(ps[2]+ps[3])) * (1.0f/256.0f);
    }
  }
  __syncthreads();
  const float* wr = w + (size_t)o*2048;
  float acc=0.f;
  for (int c=0;c<2048;++c) acc = fmaf(wr[c], sh[c], acc);
  y1[(size_t)b*512+o] = lrelu(fmaf(acc, BN_INV*g[o], bb[o]));
}

// ---------------- lin2 + lin3 fused (y2 stays in LDS) ----------------
__global__ __launch_bounds__(256) void lin23_kernel(const float* __restrict__ y1,
    const float* __restrict__ w2, const float* __restrict__ lb2,
    const float* __restrict__ g, const float* __restrict__ bb,
    const float* __restrict__ w3, const float* __restrict__ lb3,
    float* __restrict__ outp){
  __shared__ float sh1[512];
  __shared__ float sh2[256];
  int b = blockIdx.x; int o = threadIdx.x;
  for (int e=o; e<512; e+=256) sh1[e]=y1[(size_t)b*512+e];
  __syncthreads();
  {
    const float* wr = w2 + (size_t)o*512;
    float acc=0.f;
    for (int c=0;c<512;++c) acc = fmaf(wr[c], sh1[c], acc);
    acc += lb2[o];
    sh2[o] = lrelu(fmaf(acc, BN_INV*g[o], bb[o]));
  }
  __syncthreads();
  if (o < 40){
    const float* wr = w3 + (size_t)o*256;
    float acc=0.f;
    for (int c=0;c<256;++c) acc = fmaf(wr[c], sh2[c], acc);
    outp[(size_t)b*40+o] = acc + lb3[o];
  }
}

extern "C" void kernel_launch(void* const* d_in, const int* in_sizes, int n_in,
                              void* d_out, int out_size, void* d_ws, size_t ws_size,
                              hipStream_t stream) {
  const float* x      = (const float*)d_in[0];
  const float* conv1w = (const float*)d_in[1];
  const float* bn1g   = (const float*)d_in[2];
  const float* bn1b   = (const float*)d_in[3];
  const float* conv2w = (const float*)d_in[4];
  const float* bn2g   = (const float*)d_in[5];
  const float* bn2b   = (const float*)d_in[6];
  const float* conv3w = (const float*)d_in[7];
  const float* bn3g   = (const float*)d_in[8];
  const float* bn3b   = (const float*)d_in[9];
  const float* conv5w = (const float*)d_in[10];
  const float* bn5g   = (const float*)d_in[11];
  const float* bn5b   = (const float*)d_in[12];
  const float* lin1w  = (const float*)d_in[13];
  const float* bn6g   = (const float*)d_in[14];
  const float* bn6b   = (const float*)d_in[15];
  const float* lin2w  = (const float*)d_in[16];
  const float* lin2b  = (const float*)d_in[17];
  const float* bn7g   = (const float*)d_in[18];
  const float* bn7b   = (const float*)d_in[19];
  const float* lin3w  = (const float*)d_in[20];
  const float* lin3b  = (const float*)d_in[21];
  float* outp = (float*)d_out;

  char* ws = (char*)d_ws;
  size_t off = 0;
  auto alloc = [&](size_t bytes)->char*{
    off = (off + 255) & ~(size_t)255;
    char* p = ws + off; off += bytes; return p;
  };
  const int B=16, N1=1024, N2=512, N3=256;
  float* pts1 = (float*)alloc((size_t)B*N1*3*4);
  int*   ieu1 = (int*)alloc((size_t)B*N1*KNB*4);
  float* eig1 = (float*)alloc((size_t)B*N1*3*4);
  float* x1   = (float*)alloc((size_t)B*N1*64*4);
  int*   id2  = (int*)alloc((size_t)B*N2*4);
  float* pts2 = (float*)alloc((size_t)B*N2*3*4);
  float* x1d  = (float*)alloc((size_t)B*N2*64*4);
  int*   ieu2 = (int*)alloc((size_t)B*N2*KNB*4);
  float* eig2 = (float*)alloc((size_t)B*N2*3*4);
  float* x2   = (float*)alloc((size_t)B*N2*64*4);
  int*   id3  = (int*)alloc((size_t)B*N3*4);
  float* pts3 = (float*)alloc((size_t)B*N3*3*4);
  float* x2d  = (float*)alloc((size_t)B*N3*64*4);
  float* x1dd = (float*)alloc((size_t)B*N3*64*4);
  int*   ieu3 = (int*)alloc((size_t)B*N3*KNB*4);
  float* eig3 = (float*)alloc((size_t)B*N3*3*4);
  float* x3   = (float*)alloc((size_t)B*N3*128*4);
  float* pmax = (float*)alloc((size_t)B*1024*4*4);
  float* psum = (float*)alloc((size_t)B*1024*4*4);
  float* y1   = (float*)alloc((size_t)B*512*4);
  float* Wc2  = (float*)alloc((size_t)3*64*64*4);
  float* Wc3  = (float*)alloc((size_t)3*128*64*4);
  float* PQR2 = (float*)alloc((size_t)3*B*N2*64*4);
  float* PQR3 = (float*)alloc((size_t)3*B*N3*128*4);

  prep_kernel<<<112, 256, 0, stream>>>(x, pts1, conv2w, Wc2, conv3w, Wc3);
  knn_kernel<1024><<<dim3(256,16), 256, 0, stream>>>(pts1, ieu1);
  cov_eig_kernel<1024><<<(B*N1+255)/256, 256, 0, stream>>>(pts1, ieu1, eig1);
  // fps1 || (knn_ei1 + stage1)
  mega1_kernel<<<16 + 4096, 256, 0, stream>>>(pts1, id2, eig1, ieu1, conv1w, bn1g, bn1b, x1);
  gather2_kernel<<<2080, 256, 0, stream>>>(pts1, x1, id2, pts2, x1d);
  knn_kernel<512><<<dim3(128,16), 256, 0, stream>>>(pts2, ieu2);
  cov_eig_kernel<512><<<(B*N2+255)/256, 256, 0, stream>>>(pts2, ieu2, eig2);
  gemm_xw_kernel<64><<<dim3(B*N2/64, 1, 3), 256, 0, stream>>>(x1d, Wc2, PQR2, B*N2);
  // fps2 || gathermax2
  gmfps_kernel<64,512,256><<<16 + 2048, 256, 0, stream>>>(eig2, pts2, PQR2, B*N2, ieu2, bn2g, bn2b, x2, id3);
  gather3_kernel<<<2064, 256, 0, stream>>>(pts2, x2, x1d, id3, pts3, x2d, x1dd);
  knn_kernel<256><<<dim3(64,16), 256, 0, stream>>>(pts3, ieu3);
  cov_eig_kernel<256><<<(B*N3+255)/256, 256, 0, stream>>>(pts3, ieu3, eig3);
  gemm_xw_kernel<128><<<dim3(B*N3/64, 2, 3), 256, 0, stream>>>(x2d, Wc3, PQR3, B*N3);
  knn_ei_gm_kernel<128,256><<<dim3(64,16), 256, 0, stream>>>(eig3, PQR3, B*N3, ieu3, bn3g, bn3b, x3);
  conv5_gemm_kernel<<<dim3(16,4,16), 256, 0, stream>>>(x1dd, x2d, x3, conv5w, bn5g, bn5b, pmax, psum);
  lin1_kernel<<<dim3(2,16), 256, 0, stream>>>(pmax, psum, lin1w, bn6g, bn6b, y1);
  lin23_kernel<<<16, 256, 0, stream>>>(y1, lin2w, lin2b, bn7g, bn7b, lin3w, lin3b, outp);
}